// Round 1
// baseline (551.178 us; speedup 1.0000x reference)
//
#include <hip/hip_runtime.h>
#include <hip/hip_bf16.h>
#include <cstdint>
#include <cstddef>

// Problem constants (B, S, INP, HID) from the reference
#define B_   64
#define S_   2048
#define INP_ 512
#define HID_ 512

typedef float          floatx4  __attribute__((ext_vector_type(4)));
typedef __bf16         bf16x8   __attribute__((ext_vector_type(8)));
typedef unsigned short ushortx8 __attribute__((ext_vector_type(8)));

__device__ __forceinline__ unsigned short f2bf(float f) {
  unsigned u = __float_as_uint(f);
  u += 0x7FFFu + ((u >> 16) & 1u);          // round-to-nearest-even
  return (unsigned short)(u >> 16);
}
// tanh(x) = 1 - 2/(exp(2x)+1); exp(2x) = exp2(x * 2*log2(e)).  ~1e-6 accuracy, inf-safe.
__device__ __forceinline__ float fast_tanh(float x) {
  float u = __builtin_amdgcn_exp2f(x * 2.88539008177792681472f);
  return 1.0f - 2.0f * __builtin_amdgcn_rcpf(u + 1.0f);
}

// async global->LDS, 16B per lane.  LDS dest must be the WAVE-UNIFORM base
// (HW adds lane*16 itself); global source is per-lane.
__device__ __forceinline__ void gload_lds16(const float* g, float* l) {
  __builtin_amdgcn_global_load_lds(
      (const __attribute__((address_space(1))) unsigned int*)(const void*)g,
      (__attribute__((address_space(3))) unsigned int*)(void*)l, 16, 0, 0);
}

// ---------------------------------------------------------------------------
// rowdot: out[b,h] = bias[h] + dot(W[h,:], vec[b,:]), wave-per-h.
// NPART=0: vec = vecs[b, 0..511]
// NPART=1: vec[k] = sum_{c<nch} vecs[(c*B+b)*512 + k]   (partial-sum reduce)
// grid (HID_/64, B_), 256 threads (4 waves x 16 h each).
// ---------------------------------------------------------------------------
template<int NPART>
__global__ __launch_bounds__(256) void rowdot_kernel(
    const float* __restrict__ W, const float* __restrict__ bias,
    const float* __restrict__ vecs, float* __restrict__ out, int nch)
{
  __shared__ float vs[512];
  const int b = blockIdx.y, t = threadIdx.x;
  const int w = t >> 6, lane = t & 63;
  for (int i = t; i < 512; i += 256) {
    float s;
    if (NPART) {
      s = 0.0f;
      for (int c = 0; c < nch; ++c)
        s += vecs[((size_t)c * B_ + b) * INP_ + i];
    } else {
      s = vecs[(size_t)b * 512 + i];
    }
    vs[i] = s;
  }
  __syncthreads();
  float vl[8];
  #pragma unroll
  for (int j = 0; j < 8; ++j) vl[j] = vs[lane * 8 + j];
  const int h0 = blockIdx.x * 64 + w * 16;
  #pragma unroll
  for (int i = 0; i < 16; ++i) {
    const int h = h0 + i;
    const float4* wr = (const float4*)(W + (size_t)h * 512 + lane * 8);
    float4 w0 = wr[0], w1 = wr[1];
    float d = w0.x*vl[0] + w0.y*vl[1] + w0.z*vl[2] + w0.w*vl[3]
            + w1.x*vl[4] + w1.y*vl[5] + w1.z*vl[6] + w1.w*vl[7];
    #pragma unroll
    for (int off = 32; off; off >>= 1) d += __shfl_xor(d, off);
    if (lane == 0) out[(size_t)b * 512 + h] = bias[h] + d;
  }
}

// ---------------------------------------------------------------------------
// pack Wc (fp32 [HID][INP]) -> bf16 in MFMA A-fragment lane order so each
// A-frag load in the GEMM is one contiguous 16B load per lane.
// pk[(m16*1024 + ks*64 + lane)*8 + j] = Wc[m16*16 + (lane&15)][ks*32 + (lane>>4)*8 + j]
// ---------------------------------------------------------------------------
__global__ void pack_wc_kernel(const float* __restrict__ Wc, unsigned short* __restrict__ pk)
{
  int g = blockIdx.x * 256 + threadIdx.x;       // 32768 threads
  int l = g & 63, ks = (g >> 6) & 15, m16 = g >> 10;
  int row = m16 * 16 + (l & 15);
  int kb  = ks * 32 + (l >> 4) * 8;
  const float4* s = (const float4*)(Wc + (size_t)row * 512 + kb);
  float4 a = s[0], c = s[1];
  ushortx8 o = { f2bf(a.x), f2bf(a.y), f2bf(a.z), f2bf(a.w),
                 f2bf(c.x), f2bf(c.y), f2bf(c.z), f2bf(c.w) };
  *(ushortx8*)(pk + (size_t)g * 8) = o;
}

// ---------------------------------------------------------------------------
// att GEMM: per (b, s-tile of 64): ctx[h,s] = sum_k Wc[h,k]*context[b,s,k];
// att[b,s] = sum_h V[h]*tanh(hid[b,h] + ctx[h,s] + bc[h]).  No ctx store.
// Staging: context tile kept FP32 in LDS via global_load_lds (16B/lane,
// no VALU round-trip).  Source addresses pre-swizzled (chunk ^= row&7) so the
// linear DMA writes land swizzled; B-frag reads apply the same involution.
// bf16 conversion happens at fragment build (v_cvt_pk_bf16_f32), amortized
// over 8 MFMAs per fragment.
// ---------------------------------------------------------------------------
__global__ __launch_bounds__(256, 2) void att_gemm_kernel(
    const float* __restrict__ context, const unsigned short* __restrict__ Wc_pk,
    const float* __restrict__ hid, const float* __restrict__ bc,
    const float* __restrict__ V, float* __restrict__ att)
{
  __shared__ alignas(16) float bsf[64 * 128];   // 32 KB fp32 tile, swizzled
  __shared__ float hid_sm[512];
  __shared__ float V_sm[512];
  __shared__ float bc_sm[512];
  __shared__ float att_sm[64];

  const int b    = blockIdx.y;
  const int s0   = blockIdx.x * 64;
  const int t    = threadIdx.x;
  const int lane = t & 63;
  const int w    = t >> 6;          // wave id: h-rows [w*128, w*128+128)
  const int quad = lane >> 4;
  const int l15  = lane & 15;

  for (int i = t; i < 512; i += 256) {
    hid_sm[i] = hid[b * 512 + i];
    V_sm[i]   = V[i];
    bc_sm[i]  = bc[i];
  }
  if (t < 64) att_sm[t] = 0.0f;

  floatx4 acc[8][4];
  #pragma unroll
  for (int m = 0; m < 8; ++m)
    #pragma unroll
    for (int n = 0; n < 4; ++n) { floatx4 z = {0.f,0.f,0.f,0.f}; acc[m][n] = z; }

  const unsigned short* apBase = Wc_pk + (size_t)(w * 8) * 8192 + lane * 8;
  const float* src = context + ((size_t)b * S_ + s0) * INP_;

  for (int phase = 0; phase < 4; ++phase) {
    __syncthreads();                 // previous phase's readers done
    // stage context[b, s0..s0+64)[phase*128 .. +128) -> fp32 LDS, DMA.
    // issue i: wave-uniform LDS base (w*8+i)*1024 bytes; lane covers
    // row = (w*8+i)*2 + (lane>>5), position p = lane&31 (16B chunks),
    // fetching global chunk c = p ^ (row&7)  (involution).
    #pragma unroll
    for (int i = 0; i < 8; ++i) {
      const int row = (w * 8 + i) * 2 + (lane >> 5);
      const int c   = (lane & 31) ^ (row & 7);
      gload_lds16(src + (size_t)row * INP_ + phase * 128 + c * 4,
                  &bsf[(w * 8 + i) * 256]);
    }
    __syncthreads();                 // vmcnt(0) drained before barrier
    #pragma unroll
    for (int ksl = 0; ksl < 4; ++ksl) {
      const int ksg = phase * 4 + ksl;
      bf16x8 bfr[4];
      #pragma unroll
      for (int n = 0; n < 4; ++n) {
        const int row = n * 16 + l15;
        const int cb  = ksl * 8 + quad * 2;            // 4-float chunk index
        const int p0  = cb ^ (row & 7);
        const int p1  = (cb + 1) ^ (row & 7);
        floatx4 f0 = *(const floatx4*)(&bsf[row * 128 + p0 * 4]);
        floatx4 f1 = *(const floatx4*)(&bsf[row * 128 + p1 * 4]);
        bf16x8 r;
        r[0] = (__bf16)f0[0]; r[1] = (__bf16)f0[1];
        r[2] = (__bf16)f0[2]; r[3] = (__bf16)f0[3];
        r[4] = (__bf16)f1[0]; r[5] = (__bf16)f1[1];
        r[6] = (__bf16)f1[2]; r[7] = (__bf16)f1[3];
        bfr[n] = r;
      }
      #pragma unroll
      for (int m = 0; m < 8; ++m) {
        bf16x8 af = *(const bf16x8*)(apBase + (size_t)m * 8192 + (size_t)ksg * 512);
        #pragma unroll
        for (int n = 0; n < 4; ++n)
          acc[m][n] = __builtin_amdgcn_mfma_f32_16x16x32_bf16(af, bfr[n], acc[m][n], 0, 0, 0);
      }
    }
  }

  // Epilogue: att only.  C/D layout (m89-verified): col(s)=lane&15, row(h)=quad*4+reg.
  float attacc[4] = {0.f, 0.f, 0.f, 0.f};
  #pragma unroll
  for (int m = 0; m < 8; ++m) {
    const int hb = w * 128 + m * 16 + quad * 4;
    #pragma unroll
    for (int r = 0; r < 4; ++r) {
      const int h = hb + r;
      const float base = hid_sm[h] + bc_sm[h];
      const float vv = V_sm[h];
      #pragma unroll
      for (int n = 0; n < 4; ++n)
        attacc[n] += vv * fast_tanh(base + acc[m][n][r]);
    }
  }
  #pragma unroll
  for (int n = 0; n < 4; ++n) {
    float v = attacc[n];
    v += __shfl_xor(v, 16);
    v += __shfl_xor(v, 32);
    if (lane < 16) atomicAdd(&att_sm[n * 16 + l15], v);
  }
  __syncthreads();
  if (t < 64) att[b * S_ + s0 + t] = att_sm[t];
}

// ---------------------------------------------------------------------------
// masked softmax over S per batch row (unchanged from verified version).
// ---------------------------------------------------------------------------
__global__ void softmax_kernel(const void* __restrict__ mask,
                               const float* __restrict__ att,
                               float* __restrict__ alpha)
{
  __shared__ int flags;
  __shared__ float red[8];
  const int b = blockIdx.x, t = threadIdx.x;
  const int lane = t & 63, w = t >> 6;
  if (t == 0) flags = 0;
  __syncthreads();
  int f = 0;
  const unsigned* mw = (const unsigned*)mask;
  for (int i = t; i < 512; i += 256) {
    unsigned v = mw[i];
    if (v > 1u) f |= 1;                               // not plain int32 0/1
    if (v != 0u && v != 0x3f800000u) f |= 2;          // not float32 0.0/1.0
  }
  if (f) atomicOr(&flags, f);
  __syncthreads();
  const int fl = flags;
  const int mode = ((fl & 1) == 0) ? 0 : (((fl & 2) == 0) ? 1 : 2);

  float v[8]; bool msk[8];
  float vmax = -1e30f;
  #pragma unroll
  for (int i = 0; i < 8; ++i) {
    int idx = i * 256 + t;
    bool m;
    if (mode == 0)      m = ((const int*)mask)[b * S_ + idx] != 0;
    else if (mode == 1) m = ((const float*)mask)[b * S_ + idx] != 0.0f;
    else                m = ((const unsigned char*)mask)[b * S_ + idx] != 0;
    msk[i] = m;
    v[i] = att[b * S_ + idx];
    if (!m) vmax = fmaxf(vmax, v[i]);
  }
  #pragma unroll
  for (int off = 32; off; off >>= 1) vmax = fmaxf(vmax, __shfl_xor(vmax, off));
  if (lane == 0) red[w] = vmax;
  __syncthreads();
  vmax = fmaxf(fmaxf(red[0], red[1]), fmaxf(red[2], red[3]));

  float e[8], s = 0.0f;
  #pragma unroll
  for (int i = 0; i < 8; ++i) {
    e[i] = msk[i] ? 0.0f : __builtin_amdgcn_exp2f((v[i] - vmax) * 1.4426950408889634f);
    s += e[i];
  }
  #pragma unroll
  for (int off = 32; off; off >>= 1) s += __shfl_xor(s, off);
  if (lane == 0) red[4 + w] = s;
  __syncthreads();
  s = red[4] + red[5] + red[6] + red[7];
  float rinv = 1.0f / s;
  #pragma unroll
  for (int i = 0; i < 8; ++i)
    alpha[b * S_ + i * 256 + t] = e[i] * rinv;
}

// ---------------------------------------------------------------------------
// cbar partials: partial[c][b][k] = sum_{s in chunk c} alpha[b,s]*context[b,s,k]
// (linearity: hidden = Wc @ cbar + bc since sum_s alpha = 1).
// grid (nch, B_), 256 threads; thread owns k pair (2 floats).
// ---------------------------------------------------------------------------
__global__ __launch_bounds__(256) void cbar_kernel(
    const float* __restrict__ context, const float* __restrict__ alpha,
    float* __restrict__ partial, int rows)
{
  __shared__ float a_sm[2048];
  const int b = blockIdx.y, c = blockIdx.x, t = threadIdx.x;
  const int s0 = c * rows;
  for (int i = t; i < rows; i += 256) a_sm[i] = alpha[(size_t)b * S_ + s0 + i];
  __syncthreads();
  const float* base = context + ((size_t)b * S_ + s0) * INP_ + t * 2;
  float ax = 0.f, ay = 0.f;
  #pragma unroll 8
  for (int s = 0; s < rows; ++s) {
    float2 v = *(const float2*)(base + (size_t)s * INP_);
    float a = a_sm[s];
    ax = fmaf(a, v.x, ax);
    ay = fmaf(a, v.y, ay);
  }
  float2 o; o.x = ax; o.y = ay;
  *(float2*)(partial + ((size_t)c * B_ + b) * INP_ + t * 2) = o;
}

// ---------------------------------------------------------------------------
extern "C" void kernel_launch(void* const* d_in, const int* in_sizes, int n_in,
                              void* d_out, int out_size, void* d_ws, size_t ws_size,
                              hipStream_t stream)
{
  const float* inp     = (const float*)d_in[0];
  const float* context = (const float*)d_in[1];
  const void*  mask    = d_in[2];
  const float* Wl      = (const float*)d_in[3];
  const float* bl      = (const float*)d_in[4];
  const float* Wc      = (const float*)d_in[5];
  const float* bc      = (const float*)d_in[6];
  const float* V       = (const float*)d_in[7];

  float* hidden = (float*)d_out;                 // [B, HID]
  float* alpha  = (float*)d_out + B_ * HID_;     // [B, S]

  char* ws = (char*)d_ws;
  const size_t HIDW_BYTES = (size_t)B_ * HID_ * 4;      // 128 KB
  const size_t ATT_BYTES  = (size_t)B_ * S_ * 4;        // 512 KB
  const size_t PK_BYTES   = (size_t)HID_ * INP_ * 2;    // 512 KB

  float* hid_ws      = (float*)ws;
  float* att_ws      = (float*)(ws + HIDW_BYTES);
  unsigned short* pk = (unsigned short*)(ws + HIDW_BYTES + ATT_BYTES);
  float* partial     = (float*)(ws + HIDW_BYTES + ATT_BYTES + PK_BYTES);

  const size_t rem = ws_size - (HIDW_BYTES + ATT_BYTES + PK_BYTES);
  int nch = 16;                                   // s-chunks for cbar partials
  while (nch > 1 && (size_t)nch * B_ * INP_ * 4 > rem) nch >>= 1;
  const int rows = S_ / nch;

  rowdot_kernel<0><<<dim3(HID_ / 64, B_), 256, 0, stream>>>(Wl, bl, inp, hid_ws, 0);
  pack_wc_kernel<<<128, 256, 0, stream>>>(Wc, pk);
  att_gemm_kernel<<<dim3(S_ / 64, B_), 256, 0, stream>>>(context, pk, hid_ws, bc, V, att_ws);
  softmax_kernel<<<B_, 256, 0, stream>>>(mask, att_ws, alpha);
  cbar_kernel<<<dim3(nch, B_), 256, 0, stream>>>(context, alpha, partial, rows);
  rowdot_kernel<1><<<dim3(HID_ / 64, B_), 256, 0, stream>>>(Wc, bc, partial, hidden, nch);
}